// Round 1
// baseline (1638.124 us; speedup 1.0000x reference)
//
#include <hip/hip_runtime.h>

#define NNODES 100000
#define NEDGES 1600000
#define FDIM 128
#define EDIM 32
#define NCLS 17
#define ROW 72   // per-node row: [0,32) embed | [32,52) lin (17 used) | [52,72) sq (17 used)

// ---------------- Kernel A: per-node embed + lin + sq ----------------
// 8 nodes per 256-thread block. thread (n=tid>>5, c=tid&31).
__global__ __launch_bounds__(256) void node_kernel(
    const float* __restrict__ features,
    const float* __restrict__ W_embed,
    const float* __restrict__ b_embed,
    const float* __restrict__ W_trans,
    float* __restrict__ nodetab)
{
  __shared__ float sW[FDIM * EDIM];      // 16 KB
  __shared__ float sF[8 * FDIM];         // 4 KB
  __shared__ float sE[8 * EDIM];         // 1 KB
  __shared__ float sWt[2 * EDIM * NCLS]; // 4.25 KB (full W_trans)
  int tid = threadIdx.x;
  for (int i = tid; i < FDIM * EDIM / 4; i += 256)
    ((float4*)sW)[i] = ((const float4*)W_embed)[i];
  for (int i = tid; i < 2 * EDIM * NCLS; i += 256)
    sWt[i] = W_trans[i];
  int node0 = blockIdx.x * 8;
  ((float4*)sF)[tid] = ((const float4*)(features + (size_t)node0 * FDIM))[tid];
  __syncthreads();

  int n = tid >> 5, c = tid & 31;
  float acc = b_embed[c];
  const float* f = sF + n * FDIM;
  #pragma unroll 8
  for (int k = 0; k < FDIM; ++k)
    acc = fmaf(f[k], sW[k * EDIM + c], acc);   // sW: banks 0..31, conflict-free; sF: broadcast
  int node = node0 + n;
  nodetab[(size_t)node * ROW + c] = acc;
  sE[n * EDIM + c] = acc;
  __syncthreads();

  if (c < NCLS) {
    const float* e = sE + n * EDIM;
    float lin = 0.f, sq = 0.f;
    #pragma unroll
    for (int k = 0; k < EDIM; ++k) {
      float ek = e[k];
      lin = fmaf(ek,      sWt[k * NCLS + c],          lin);
      sq  = fmaf(ek * ek, sWt[(EDIM + k) * NCLS + c], sq);
    }
    nodetab[(size_t)node * ROW + 32 + c] = lin;
    nodetab[(size_t)node * ROW + 52 + c] = sq;
  }
}

// ---------------- Kernel B: per-edge softmax + scatter ----------------
__global__ __launch_bounds__(256) void edge_kernel(
    const int*   __restrict__ edges,
    const float* __restrict__ weights,
    const float* __restrict__ W_trans,
    const float* __restrict__ b_trans,
    const float* __restrict__ nodetab,
    float* __restrict__ poss_edge,
    float* __restrict__ recall)
{
  __shared__ float sOut[256 * NCLS];   // 17 KB staging for coalesced poss_edge write
  int tid = threadIdx.x;
  int e = blockIdx.x * 256 + tid;
  int2 ed = ((const int2*)edges)[e];
  int src = ed.x, dst = ed.y;
  const float* rs = nodetab + (size_t)src * ROW;
  const float* rd = nodetab + (size_t)dst * ROW;

  float cross[NCLS];
  #pragma unroll
  for (int c2 = 0; c2 < NCLS; ++c2) cross[c2] = 0.f;

  // cross = (s .* d) @ W2   (W2 = rows 32..63 of W_trans; wave-uniform -> s_loads)
  #pragma unroll
  for (int k4 = 0; k4 < EDIM / 4; ++k4) {
    float4 a = ((const float4*)rs)[k4];
    float4 b = ((const float4*)rd)[k4];
    float p0 = a.x * b.x, p1 = a.y * b.y, p2 = a.z * b.z, p3 = a.w * b.w;
    #pragma unroll
    for (int c2 = 0; c2 < NCLS; ++c2) {
      cross[c2] = fmaf(p0, W_trans[(EDIM + 4 * k4 + 0) * NCLS + c2], cross[c2]);
      cross[c2] = fmaf(p1, W_trans[(EDIM + 4 * k4 + 1) * NCLS + c2], cross[c2]);
      cross[c2] = fmaf(p2, W_trans[(EDIM + 4 * k4 + 2) * NCLS + c2], cross[c2]);
      cross[c2] = fmaf(p3, W_trans[(EDIM + 4 * k4 + 3) * NCLS + c2], cross[c2]);
    }
  }

  float lgt[NCLS];
  float m = -1e30f;
  #pragma unroll
  for (int c2 = 0; c2 < NCLS; ++c2) {
    float v = 0.5f * (rs[32 + c2] + rd[32 + c2]) + rs[52 + c2] + rd[52 + c2]
            - 2.f * cross[c2] + b_trans[c2];
    lgt[c2] = v;
    m = fmaxf(m, v);
  }
  float sum = 0.f;
  #pragma unroll
  for (int c2 = 0; c2 < NCLS; ++c2) { lgt[c2] = __expf(lgt[c2] - m); sum += lgt[c2]; }
  float inv = 1.0f / sum;
  float w  = weights[e];
  float wi = w * inv;

  #pragma unroll
  for (int c2 = 0; c2 < NCLS; ++c2) {
    sOut[tid * NCLS + c2] = lgt[c2] * inv;              // stride 17 (odd) -> conflict-free
    atomicAdd(recall + (size_t)src * NCLS + c2, lgt[c2] * wi);
  }
  __syncthreads();
  float* outp = poss_edge + (size_t)blockIdx.x * 256 * NCLS;
  for (int i = tid; i < 256 * NCLS; i += 256)
    outp[i] = sOut[i];
}

// ---------------- Kernel C: poss_node = recall / nsum ----------------
__global__ __launch_bounds__(256) void div_kernel(
    const float* __restrict__ recall,
    const float* __restrict__ nsum,
    float* __restrict__ poss_node)
{
  int i = blockIdx.x * 256 + threadIdx.x;
  if (i < NNODES * NCLS)
    poss_node[i] = recall[i] / nsum[i / NCLS];
}

extern "C" void kernel_launch(void* const* d_in, const int* in_sizes, int n_in,
                              void* d_out, int out_size, void* d_ws, size_t ws_size,
                              hipStream_t stream) {
  const float* features = (const float*)d_in[0];
  const int*   edges    = (const int*)d_in[1];
  const float* weights  = (const float*)d_in[2];
  const float* nsum     = (const float*)d_in[3];
  const float* W_embed  = (const float*)d_in[4];
  const float* b_embed  = (const float*)d_in[5];
  const float* W_trans  = (const float*)d_in[6];
  const float* b_trans  = (const float*)d_in[7];

  float* out       = (float*)d_out;
  float* poss_node = out;
  float* poss_edge = out + (size_t)NNODES * NCLS;
  float* recall    = out + (size_t)(NNODES + NEDGES) * NCLS;
  float* nodetab   = (float*)d_ws;   // 100000 * 72 * 4 = 28.8 MB

  hipMemsetAsync(recall, 0, (size_t)NNODES * NCLS * sizeof(float), stream);
  node_kernel<<<NNODES / 8, 256, 0, stream>>>(features, W_embed, b_embed, W_trans, nodetab);
  edge_kernel<<<NEDGES / 256, 256, 0, stream>>>(edges, weights, W_trans, b_trans,
                                                nodetab, poss_edge, recall);
  div_kernel<<<(NNODES * NCLS + 255) / 256, 256, 0, stream>>>(recall, nsum, poss_node);
}

// Round 2
// 455.555 us; speedup vs baseline: 3.5959x; 3.5959x over previous
//
#include <hip/hip_runtime.h>

#define NNODES 100000
#define NEDGES 1600000
#define FDIM 128
#define EDIM 32
#define NCLS 17
#define ROW 64   // per-node row (floats): [0,32) embed | [32,49) h = 0.5*lin + sq | pad
                 // 256 B = exactly 4 aligned cachelines per row.

// ---------------- Kernel A: per-node embed + h ----------------
// 8 nodes per 256-thread block. thread (n=tid>>5, c=tid&31).
__global__ __launch_bounds__(256) void node_kernel(
    const float* __restrict__ features,
    const float* __restrict__ W_embed,
    const float* __restrict__ b_embed,
    const float* __restrict__ W_trans,
    float* __restrict__ nodetab)
{
  __shared__ float sW[FDIM * EDIM];      // 16 KB
  __shared__ float sF[8 * FDIM];         // 4 KB
  __shared__ float sE[8 * EDIM];         // 1 KB
  __shared__ float sWt[2 * EDIM * NCLS]; // 4.25 KB (full W_trans)
  int tid = threadIdx.x;
  for (int i = tid; i < FDIM * EDIM / 4; i += 256)
    ((float4*)sW)[i] = ((const float4*)W_embed)[i];
  for (int i = tid; i < 2 * EDIM * NCLS; i += 256)
    sWt[i] = W_trans[i];
  int node0 = blockIdx.x * 8;
  ((float4*)sF)[tid] = ((const float4*)(features + (size_t)node0 * FDIM))[tid];
  __syncthreads();

  int n = tid >> 5, c = tid & 31;
  float acc = b_embed[c];
  const float* f = sF + n * FDIM;
  #pragma unroll 8
  for (int k = 0; k < FDIM; ++k)
    acc = fmaf(f[k], sW[k * EDIM + c], acc);   // sW: banks 0..31 conflict-free; sF: broadcast
  int node = node0 + n;
  nodetab[(size_t)node * ROW + c] = acc;
  sE[n * EDIM + c] = acc;
  __syncthreads();

  if (c < NCLS) {
    const float* e = sE + n * EDIM;
    float lin = 0.f, sq = 0.f;
    #pragma unroll
    for (int k = 0; k < EDIM; ++k) {
      float ek = e[k];
      lin = fmaf(ek,      sWt[k * NCLS + c],          lin);
      sq  = fmaf(ek * ek, sWt[(EDIM + k) * NCLS + c], sq);
    }
    nodetab[(size_t)node * ROW + 32 + c] = 0.5f * lin + sq;
  }
}

// ---------------- Kernel B: per-edge softmax + coalesced scatter ----------------
__global__ __launch_bounds__(256, 4) void edge_kernel(
    const int*   __restrict__ edges,
    const float* __restrict__ weights,
    const float* __restrict__ W_trans,
    const float* __restrict__ b_trans,
    const float* __restrict__ nodetab,
    float* __restrict__ poss_edge,
    float* __restrict__ recall)
{
  __shared__ float sOut[256 * NCLS];   // 17 KB staging (poss phase, then value phase)
  __shared__ int   sSrc[256];
  int tid = threadIdx.x;
  int e = blockIdx.x * 256 + tid;
  int2 ed = ((const int2*)edges)[e];
  int src = ed.x, dst = ed.y;
  const float* rs = nodetab + (size_t)src * ROW;
  const float* rd = nodetab + (size_t)dst * ROW;

  // logits = h_s + h_d + b  - 2*(s.*d)@W2
  float lgt[NCLS];
  #pragma unroll
  for (int c = 0; c < NCLS; ++c)
    lgt[c] = rs[32 + c] + rd[32 + c] + b_trans[c];

  #pragma unroll
  for (int k4 = 0; k4 < EDIM / 4; ++k4) {
    float4 a = ((const float4*)rs)[k4];
    float4 b = ((const float4*)rd)[k4];
    float p0 = -2.f * a.x * b.x, p1 = -2.f * a.y * b.y;
    float p2 = -2.f * a.z * b.z, p3 = -2.f * a.w * b.w;
    #pragma unroll
    for (int c = 0; c < NCLS; ++c) {
      lgt[c] = fmaf(p0, W_trans[(EDIM + 4 * k4 + 0) * NCLS + c], lgt[c]);
      lgt[c] = fmaf(p1, W_trans[(EDIM + 4 * k4 + 1) * NCLS + c], lgt[c]);
      lgt[c] = fmaf(p2, W_trans[(EDIM + 4 * k4 + 2) * NCLS + c], lgt[c]);
      lgt[c] = fmaf(p3, W_trans[(EDIM + 4 * k4 + 3) * NCLS + c], lgt[c]);
    }
  }

  float m = lgt[0];
  #pragma unroll
  for (int c = 1; c < NCLS; ++c) m = fmaxf(m, lgt[c]);
  float sum = 0.f;
  #pragma unroll
  for (int c = 0; c < NCLS; ++c) { lgt[c] = __expf(lgt[c] - m); sum += lgt[c]; }
  float inv = 1.0f / sum;
  float wi  = weights[e] * inv;

  sSrc[tid] = src;
  #pragma unroll
  for (int c = 0; c < NCLS; ++c) sOut[tid * NCLS + c] = lgt[c] * inv;
  __syncthreads();

  // phase 1: coalesced float4 poss_edge store
  float4* outp = (float4*)(poss_edge + (size_t)blockIdx.x * 256 * NCLS);
  const float4* sOut4 = (const float4*)sOut;
  for (int i = tid; i < 256 * NCLS / 4; i += 256)
    outp[i] = sOut4[i];
  __syncthreads();

  // phase 2: restage value = poss * w, then lane-transposed atomics
  #pragma unroll
  for (int c = 0; c < NCLS; ++c) sOut[tid * NCLS + c] = lgt[c] * wi;
  __syncthreads();

  for (int i = tid; i < 256 * NCLS; i += 256) {
    unsigned e2 = (unsigned)i / NCLS;          // consecutive lanes -> same edge,
    unsigned c2 = (unsigned)i - e2 * NCLS;     // consecutive classes -> coalesced lines
    atomicAdd(recall + (size_t)sSrc[e2] * NCLS + c2, sOut[i]);
  }
}

// ---------------- Kernel C: poss_node = recall / nsum ----------------
__global__ __launch_bounds__(256) void div_kernel(
    const float* __restrict__ recall,
    const float* __restrict__ nsum,
    float* __restrict__ poss_node)
{
  int i = blockIdx.x * 256 + threadIdx.x;
  if (i < NNODES * NCLS)
    poss_node[i] = recall[i] / nsum[i / NCLS];
}

extern "C" void kernel_launch(void* const* d_in, const int* in_sizes, int n_in,
                              void* d_out, int out_size, void* d_ws, size_t ws_size,
                              hipStream_t stream) {
  const float* features = (const float*)d_in[0];
  const int*   edges    = (const int*)d_in[1];
  const float* weights  = (const float*)d_in[2];
  const float* nsum     = (const float*)d_in[3];
  const float* W_embed  = (const float*)d_in[4];
  const float* b_embed  = (const float*)d_in[5];
  const float* W_trans  = (const float*)d_in[6];
  const float* b_trans  = (const float*)d_in[7];

  float* out       = (float*)d_out;
  float* poss_node = out;
  float* poss_edge = out + (size_t)NNODES * NCLS;
  float* recall    = out + (size_t)(NNODES + NEDGES) * NCLS;
  float* nodetab   = (float*)d_ws;   // 100000 * 64 * 4 = 25.6 MB

  hipMemsetAsync(recall, 0, (size_t)NNODES * NCLS * sizeof(float), stream);
  node_kernel<<<NNODES / 8, 256, 0, stream>>>(features, W_embed, b_embed, W_trans, nodetab);
  edge_kernel<<<NEDGES / 256, 256, 0, stream>>>(edges, weights, W_trans, b_trans,
                                                nodetab, poss_edge, recall);
  div_kernel<<<(NNODES * NCLS + 255) / 256, 256, 0, stream>>>(recall, nsum, poss_node);
}

// Round 3
// 447.695 us; speedup vs baseline: 3.6590x; 1.0176x over previous
//
#include <hip/hip_runtime.h>

#define NNODES 100000
#define NEDGES 1600000
#define FDIM 128
#define EDIM 32
#define NCLS 17
#define ROWU 32   // per-node row = 32 u32 = 128 B = 2 cachelines:
                  // u32[0..15]  : embed as 32 x bf16 (packed pairs)
                  // u32[16..24] : h = 0.5*lin + sq as 17 x bf16 (packed pairs)

typedef unsigned int u32;

__device__ inline u32 bf16r(float x) {            // round-to-nearest-even bf16
  u32 u = __float_as_uint(x);
  return (u + 0x7FFFu + ((u >> 16) & 1u)) >> 16;
}
__device__ inline u32 pk(float lo, float hi) { return bf16r(lo) | (bf16r(hi) << 16); }
__device__ inline float lo16(u32 u) { return __uint_as_float(u << 16); }
__device__ inline float hi16(u32 u) { return __uint_as_float(u & 0xFFFF0000u); }

// ---------------- Kernel A: per-node embed + h, thread = node, no LDS ----------------
// W indices are wave-uniform -> scalar loads; features read per-lane float4
// (each lane consumes its whole 512B row -> full line utilization via L1).
__global__ __launch_bounds__(256) void node_kernel(
    const float* __restrict__ features,
    const float* __restrict__ W_embed,   // [128][32]
    const float* __restrict__ b_embed,   // [32]
    const float* __restrict__ W_trans,   // [64][17]
    u32* __restrict__ nodetab)
{
  int n = blockIdx.x * 256 + threadIdx.x;
  if (n >= NNODES) return;

  float acc[EDIM];
  #pragma unroll
  for (int c = 0; c < EDIM; ++c) acc[c] = b_embed[c];

  const float4* f4 = (const float4*)(features + (size_t)n * FDIM);
  for (int k4 = 0; k4 < FDIM / 4; ++k4) {
    float4 f = f4[k4];
    const float* w = W_embed + k4 * 4 * EDIM;   // uniform -> s_load
    #pragma unroll
    for (int c = 0; c < EDIM; ++c) {
      acc[c] = fmaf(f.x, w[c],            acc[c]);
      acc[c] = fmaf(f.y, w[EDIM + c],     acc[c]);
      acc[c] = fmaf(f.z, w[2 * EDIM + c], acc[c]);
      acc[c] = fmaf(f.w, w[3 * EDIM + c], acc[c]);
    }
  }

  float sq[EDIM];
  #pragma unroll
  for (int k = 0; k < EDIM; ++k) sq[k] = acc[k] * acc[k];

  float h[NCLS + 1];
  #pragma unroll
  for (int c = 0; c < NCLS; ++c) {
    float lin = 0.f, sqs = 0.f;
    #pragma unroll
    for (int k = 0; k < EDIM; ++k) {
      lin = fmaf(acc[k], W_trans[k * NCLS + c],          lin);   // uniform -> s_load
      sqs = fmaf(sq[k],  W_trans[(EDIM + k) * NCLS + c], sqs);
    }
    h[c] = 0.5f * lin + sqs;
  }
  h[NCLS] = 0.f;

  u32* row = nodetab + (size_t)n * ROWU;
  u32 p[16];
  #pragma unroll
  for (int i = 0; i < 16; ++i) p[i] = pk(acc[2 * i], acc[2 * i + 1]);
  #pragma unroll
  for (int i = 0; i < 4; ++i)
    ((uint4*)row)[i] = make_uint4(p[4 * i], p[4 * i + 1], p[4 * i + 2], p[4 * i + 3]);
  #pragma unroll
  for (int i = 0; i < 9; ++i) row[16 + i] = pk(h[2 * i], h[2 * i + 1]);
}

// ---------------- Kernel B: per-edge softmax + coalesced scatter ----------------
__global__ __launch_bounds__(256, 4) void edge_kernel(
    const int*   __restrict__ edges,
    const float* __restrict__ weights,
    const float* __restrict__ W_trans,
    const float* __restrict__ b_trans,
    const u32*   __restrict__ nodetab,
    float* __restrict__ poss_edge,
    float* __restrict__ recall)
{
  __shared__ float sOut[256 * NCLS];   // 17 KB staging (poss phase, then value phase)
  __shared__ int   sSrc[256];
  int tid = threadIdx.x;
  int e = blockIdx.x * 256 + tid;
  int2 ed = ((const int2*)edges)[e];
  int src = ed.x, dst = ed.y;
  const uint4* rs4 = (const uint4*)(nodetab + (size_t)src * ROWU);
  const uint4* rd4 = (const uint4*)(nodetab + (size_t)dst * ROWU);

  // logits = h_s + h_d + b - 2*(s.*d)@W2   (h line: u32[16..24])
  uint4 sh0 = rs4[4], dh0 = rd4[4];
  uint4 sh1 = rs4[5], dh1 = rd4[5];
  u32   sh2 = ((const u32*)rs4)[24], dh2 = ((const u32*)rd4)[24];

  float lgt[NCLS];
  {
    u32 sp[9] = {sh0.x, sh0.y, sh0.z, sh0.w, sh1.x, sh1.y, sh1.z, sh1.w, sh2};
    u32 dp[9] = {dh0.x, dh0.y, dh0.z, dh0.w, dh1.x, dh1.y, dh1.z, dh1.w, dh2};
    #pragma unroll
    for (int i = 0; i < 8; ++i) {
      lgt[2 * i]     = lo16(sp[i]) + lo16(dp[i]) + b_trans[2 * i];
      lgt[2 * i + 1] = hi16(sp[i]) + hi16(dp[i]) + b_trans[2 * i + 1];
    }
    lgt[16] = lo16(sp[8]) + lo16(dp[8]) + b_trans[16];
  }

  // cross term, one 8-element k-slice (one uint4 pair) at a time to cap live regs
  #pragma unroll
  for (int q = 0; q < 4; ++q) {
    uint4 sa = rs4[q], da = rd4[q];
    u32 su[4] = {sa.x, sa.y, sa.z, sa.w};
    u32 du[4] = {da.x, da.y, da.z, da.w};
    float p[8];
    #pragma unroll
    for (int j = 0; j < 4; ++j) {
      p[2 * j]     = -2.f * lo16(su[j]) * lo16(du[j]);
      p[2 * j + 1] = -2.f * hi16(su[j]) * hi16(du[j]);
    }
    #pragma unroll
    for (int j = 0; j < 8; ++j) {
      const float* w = W_trans + (EDIM + q * 8 + j) * NCLS;   // uniform -> s_load
      #pragma unroll
      for (int c = 0; c < NCLS; ++c) lgt[c] = fmaf(p[j], w[c], lgt[c]);
    }
  }

  float m = lgt[0];
  #pragma unroll
  for (int c = 1; c < NCLS; ++c) m = fmaxf(m, lgt[c]);
  float sum = 0.f;
  #pragma unroll
  for (int c = 0; c < NCLS; ++c) { lgt[c] = __expf(lgt[c] - m); sum += lgt[c]; }
  float inv = 1.0f / sum;
  float wi  = weights[e] * inv;

  sSrc[tid] = src;
  #pragma unroll
  for (int c = 0; c < NCLS; ++c) sOut[tid * NCLS + c] = lgt[c] * inv;
  __syncthreads();

  // phase 1: coalesced float4 poss_edge store
  float4* outp = (float4*)(poss_edge + (size_t)blockIdx.x * 256 * NCLS);
  const float4* sOut4 = (const float4*)sOut;
  for (int i = tid; i < 256 * NCLS / 4; i += 256)
    outp[i] = sOut4[i];
  __syncthreads();

  // phase 2: restage value = poss * w, then lane-transposed coalesced atomics
  #pragma unroll
  for (int c = 0; c < NCLS; ++c) sOut[tid * NCLS + c] = lgt[c] * wi;
  __syncthreads();

  for (int i = tid; i < 256 * NCLS; i += 256) {
    unsigned e2 = (unsigned)i / NCLS;          // consecutive lanes -> same edge,
    unsigned c2 = (unsigned)i - e2 * NCLS;     // consecutive classes -> coalesced lines
    atomicAdd(recall + (size_t)sSrc[e2] * NCLS + c2, sOut[i]);
  }
}

// ---------------- Kernel C: poss_node = recall / nsum ----------------
__global__ __launch_bounds__(256) void div_kernel(
    const float* __restrict__ recall,
    const float* __restrict__ nsum,
    float* __restrict__ poss_node)
{
  int i = blockIdx.x * 256 + threadIdx.x;
  if (i < NNODES * NCLS)
    poss_node[i] = recall[i] / nsum[i / NCLS];
}

extern "C" void kernel_launch(void* const* d_in, const int* in_sizes, int n_in,
                              void* d_out, int out_size, void* d_ws, size_t ws_size,
                              hipStream_t stream) {
  const float* features = (const float*)d_in[0];
  const int*   edges    = (const int*)d_in[1];
  const float* weights  = (const float*)d_in[2];
  const float* nsum     = (const float*)d_in[3];
  const float* W_embed  = (const float*)d_in[4];
  const float* b_embed  = (const float*)d_in[5];
  const float* W_trans  = (const float*)d_in[6];
  const float* b_trans  = (const float*)d_in[7];

  float* out       = (float*)d_out;
  float* poss_node = out;
  float* poss_edge = out + (size_t)NNODES * NCLS;
  float* recall    = out + (size_t)(NNODES + NEDGES) * NCLS;
  u32*   nodetab   = (u32*)d_ws;   // 100000 * 128 B = 12.8 MB

  hipMemsetAsync(recall, 0, (size_t)NNODES * NCLS * sizeof(float), stream);
  node_kernel<<<(NNODES + 255) / 256, 256, 0, stream>>>(features, W_embed, b_embed,
                                                        W_trans, nodetab);
  edge_kernel<<<NEDGES / 256, 256, 0, stream>>>(edges, weights, W_trans, b_trans,
                                                nodetab, poss_edge, recall);
  div_kernel<<<(NNODES * NCLS + 255) / 256, 256, 0, stream>>>(recall, nsum, poss_node);
}